// Round 9
// baseline (1874.935 us; speedup 1.0000x reference)
//
#include <hip/hip_runtime.h>
#include <math.h>

#define T_TOK 8192
#define DM 1024
#define DFF 4096
#define NE 8
#define NPAIR 16384
#define MAXTILE 136
#define LN_EPS 1e-5f

typedef __attribute__((ext_vector_type(8))) short bf16x8;
typedef __attribute__((ext_vector_type(4))) float f32x4;
typedef __attribute__((ext_vector_type(4))) unsigned short u16x4;
typedef __attribute__((ext_vector_type(8))) unsigned short u16x8;
typedef unsigned int u32;
typedef unsigned short u16;

__device__ __forceinline__ u16 f2bf(float f) {
  union { float f; u32 u; } v; v.f = f;
  u32 r = (v.u + 0x7fffu + ((v.u >> 16) & 1u)) >> 16;
  return (u16)r;
}
__device__ __forceinline__ float bf2f(u16 h) {
  union { u32 u; float f; } v; v.u = ((u32)h) << 16; return v.f;
}

__device__ __forceinline__ void gll16(const void* g, void* l) {
  __builtin_amdgcn_global_load_lds(
      (const __attribute__((address_space(1))) u32*)g,
      (__attribute__((address_space(3))) u32*)l, 16, 0, 0);
}

// ---------------- embed: x = emb[tok] + sym[b]; plus split bf16 copies ----------------
__global__ __launch_bounds__(256) void embed_kernel(const int* __restrict__ tok,
    const float* __restrict__ sym, const float* __restrict__ emb,
    float* __restrict__ x, u16* __restrict__ xh, u16* __restrict__ xl)
{
  int t = blockIdx.x;
  int b = t >> 11;
  int tk = tok[t];
  int d = threadIdx.x * 4;
  f32x4 e = *(const f32x4*)(emb + (size_t)tk * DM + d);
  f32x4 s = *(const f32x4*)(sym + (size_t)b * DM + d);
  f32x4 v = e + s;
  *(f32x4*)(x + (size_t)t * DM + d) = v;
  u16x4 hv, lv;
#pragma unroll
  for (int j = 0; j < 4; ++j) {
    u16 hb = f2bf(v[j]);
    hv[j] = hb;
    lv[j] = f2bf(v[j] - bf2f(hb));
  }
  *(u16x4*)(xh + (size_t)t * DM + d) = hv;
  *(u16x4*)(xl + (size_t)t * DM + d) = lv;
}

// ---------------- layer-0 gating: f64 logits, top-2 only (no atomics) ----------------
__global__ __launch_bounds__(256) void gate_kernel(const float* __restrict__ x,
    const float* __restrict__ gw, const float* __restrict__ gb,
    int* __restrict__ topk_idx, float* __restrict__ topk_w)
{
  int lane = threadIdx.x & 63;
  int t = blockIdx.x * 4 + (threadIdx.x >> 6);
  const float* xr = x + (size_t)t * DM;
  double a[8] = {0,0,0,0,0,0,0,0};
  for (int i = 0; i < 16; ++i) {
    int d = i * 64 + lane;
    double xv = (double)xr[d];
    const float* g = gw + (size_t)d * NE;
#pragma unroll
    for (int j = 0; j < 8; ++j) a[j] += xv * (double)g[j];
  }
#pragma unroll
  for (int j = 0; j < 8; ++j) {
#pragma unroll
    for (int sh = 32; sh; sh >>= 1) a[j] += __shfl_xor(a[j], sh);
  }
  if (lane == 0) {
#pragma unroll
    for (int j = 0; j < 8; ++j) a[j] += (double)gb[j];
    double m = a[0];
    for (int j = 1; j < 8; ++j) m = a[j] > m ? a[j] : m;
    double p[8], sum = 0.0;
    for (int j = 0; j < 8; ++j) { p[j] = exp(a[j] - m); sum += p[j]; }
    for (int j = 0; j < 8; ++j) p[j] /= sum;
    int j0 = 0; double b0 = p[0];
    for (int j = 1; j < 8; ++j) if (p[j] > b0) { b0 = p[j]; j0 = j; }
    int j1 = (j0 == 0) ? 1 : 0; double b1v = p[j1];
    for (int j = 0; j < 8; ++j) if (j != j0 && p[j] > b1v) { b1v = p[j]; j1 = j; }
    topk_idx[t*2]   = j0; topk_idx[t*2+1] = j1;
    topk_w[t*2]     = (float)b0; topk_w[t*2+1] = (float)b1v;
  }
}

// meta layout (ints): [0..7]=totals, [8..16]=offsets, [31]=ntiles,
//   [32..167]=tile table ((e<<16)|mt, -1 pad), [168..423]=blockcnt[32][8],
//   [424..679]=blockbase[32][8]
__global__ __launch_bounds__(256) void count_kernel(const int* __restrict__ topk_idx,
    int* __restrict__ meta)
{
  __shared__ int hist[8];
  int tid = threadIdx.x;
  if (tid < 8) hist[tid] = 0;
  __syncthreads();
  int t = blockIdx.x * 256 + tid;
  atomicAdd(&hist[topk_idx[t*2] & 7], 1);
  atomicAdd(&hist[topk_idx[t*2+1] & 7], 1);
  __syncthreads();
  if (tid < 8) meta[168 + blockIdx.x * 8 + tid] = hist[tid];
}

__global__ __launch_bounds__(64) void scan_kernel(int* __restrict__ meta)
{
  __shared__ int tot[8], off[9], tb[8];
  int lane = threadIdx.x;
  if (lane < 8) {
    int s = 0;
    for (int b = 0; b < 32; ++b) s += meta[168 + b * 8 + lane];
    tot[lane] = s;
  }
  __syncthreads();
  if (lane == 0) {
    int s = 0, nt = 0;
    for (int e = 0; e < 8; ++e) {
      off[e] = s; s += tot[e];
      tb[e] = nt; nt += (tot[e] + 127) >> 7;
    }
    off[8] = s;
    meta[31] = nt;
    for (int i = nt; i < MAXTILE; ++i) meta[32 + i] = -1;
  }
  __syncthreads();
  if (lane < 9) meta[8 + lane] = off[lane];
  if (lane < 8) {
    meta[lane] = tot[lane];
    int n = (tot[lane] + 127) >> 7;
    for (int i = 0; i < n; ++i) meta[32 + tb[lane] + i] = (lane << 16) | i;
    int run = off[lane];
    for (int b = 0; b < 32; ++b) {
      meta[424 + b * 8 + lane] = run;
      run += meta[168 + b * 8 + lane];
    }
  }
}

// scatter via block-local LDS ranks; packs slot into topk_idx bits [3..]
__global__ __launch_bounds__(256) void scatter_kernel(int* __restrict__ topk_idx,
    const int* __restrict__ meta, int* __restrict__ pair_token)
{
  __shared__ int hist[8];
  __shared__ int base[8];
  int tid = threadIdx.x;
  if (tid < 8) { hist[tid] = 0; base[tid] = meta[424 + blockIdx.x * 8 + tid]; }
  __syncthreads();
  int t = blockIdx.x * 256 + tid;
#pragma unroll
  for (int k = 0; k < 2; ++k) {
    int e = topk_idx[t*2 + k] & 7;
    int pos = atomicAdd(&hist[e], 1);
    int slot = base[e] + pos;
    pair_token[slot] = t;
    topk_idx[t*2 + k] = e | (slot << 3);
  }
}

// ------------- weight transpose+split: f32 [K][N] -> bf16 hi/lo [N][K] -------------
template<bool LO>
__global__ __launch_bounds__(256) void transpose_kernel(const float* __restrict__ src,
    u16* __restrict__ dsth, u16* __restrict__ dstl, int K, int N)
{
  __shared__ float tile[64][65];
  int e = blockIdx.z;
  const float* s = src + (size_t)e * K * N;
  size_t dbase = (size_t)e * K * N;
  int n0 = blockIdx.x * 64, k0 = blockIdx.y * 64;
  int tid = threadIdx.x;
  int nl = tid & 63;
  int kq = tid >> 6;
#pragma unroll
  for (int j = 0; j < 16; ++j) {
    int kl = j * 4 + kq;
    tile[nl][kl] = s[(size_t)(k0 + kl) * N + n0 + nl];
  }
  __syncthreads();
#pragma unroll
  for (int it = 0; it < 2; ++it) {
    int task = it * 256 + tid;
    int nr = task >> 3;
    int ch = task & 7;
    u16x8 oh, ol;
#pragma unroll
    for (int j = 0; j < 8; ++j) {
      float v = tile[nr][ch*8 + j];
      u16 hb = f2bf(v);
      oh[j] = hb;
      if (LO) ol[j] = f2bf(v - bf2f(hb));
    }
    size_t doff = dbase + (size_t)(n0 + nr) * K + k0 + ch*8;
    *(u16x8*)(dsth + doff) = oh;
    if (LO) *(u16x8*)(dstl + doff) = ol;
  }
}

// ---- W2G[e] = w2[e] @ gw1  ([E][DFF][8], f32) ----
__global__ __launch_bounds__(256) void w2g_kernel(const float* __restrict__ w2,
    const float* __restrict__ gw, float* __restrict__ w2g)
{
  int wid = blockIdx.x * 4 + (threadIdx.x >> 6);
  int lane = threadIdx.x & 63;
  int e = wid >> 12, f = wid & 4095;
  const float* row = w2 + ((size_t)e * DFF + f) * DM;
  float a0=0,a1=0,a2=0,a3=0,a4=0,a5=0,a6=0,a7=0;
  for (int i = 0; i < 4; ++i) {
    int d0 = i * 256 + lane * 4;
    f32x4 xv = *(const f32x4*)(row + d0);
#pragma unroll
    for (int q = 0; q < 4; ++q) {
      const f32x4* gr = (const f32x4*)(gw + (size_t)(d0 + q) * 8);
      f32x4 g0 = gr[0], g1 = gr[1];
      float xq = xv[q];
      a0 += xq*g0.x; a1 += xq*g0.y; a2 += xq*g0.z; a3 += xq*g0.w;
      a4 += xq*g1.x; a5 += xq*g1.y; a6 += xq*g1.z; a7 += xq*g1.w;
    }
  }
  float acc[8] = {a0,a1,a2,a3,a4,a5,a6,a7};
#pragma unroll
  for (int j = 0; j < 8; ++j) {
#pragma unroll
    for (int sh = 32; sh; sh >>= 1) acc[j] += __shfl_xor(acc[j], sh);
  }
  if (lane == 0) {
#pragma unroll
    for (int j = 0; j < 8; ++j) w2g[(size_t)wid * 8 + j] = acc[j];
  }
}

__global__ __launch_bounds__(256) void b2g_kernel(const float* __restrict__ b2,
    const float* __restrict__ gw, float* __restrict__ b2g)
{
  int w = blockIdx.x * 4 + (threadIdx.x >> 6);
  int lane = threadIdx.x & 63;
  int e = w >> 3, j = w & 7;
  float acc = 0.f;
  for (int i = 0; i < 16; ++i) {
    int d = i * 64 + lane;
    acc += b2[(size_t)e * DM + d] * gw[(size_t)d * 8 + j];
  }
#pragma unroll
  for (int sh = 32; sh; sh >>= 1) acc += __shfl_xor(acc, sh);
  if (lane == 0) b2g[w] = acc;
}

// ---- pair logits: R[p] = (hh[p]+hl[p]) @ W2G[e(p)] ----
__global__ __launch_bounds__(256) void pairlogit_kernel(const u16* __restrict__ hh,
    const u16* __restrict__ hl, const int* __restrict__ off,
    const float* __restrict__ w2g, float* __restrict__ R)
{
  int p = blockIdx.x * 4 + (threadIdx.x >> 6);
  int lane = threadIdx.x & 63;
  int e = 0;
#pragma unroll
  for (int j = 1; j < 8; ++j) e += (p >= off[j]) ? 1 : 0;
  const float* wg = w2g + (size_t)e * DFF * 8;
  const u16* ph = hh + (size_t)p * DFF;
  const u16* pl = hl + (size_t)p * DFF;
  float a0=0,a1=0,a2=0,a3=0,a4=0,a5=0,a6=0,a7=0;
  for (int i = 0; i < 8; ++i) {
    int f0 = i * 512 + lane * 8;
    u16x8 vh = *(const u16x8*)(ph + f0);
    u16x8 vl = *(const u16x8*)(pl + f0);
#pragma unroll
    for (int q = 0; q < 8; ++q) {
      float hv = bf2f(vh[q]) + bf2f(vl[q]);
      const f32x4* wr = (const f32x4*)(wg + (size_t)(f0 + q) * 8);
      f32x4 g0 = wr[0], g1 = wr[1];
      a0 += hv*g0.x; a1 += hv*g0.y; a2 += hv*g0.z; a3 += hv*g0.w;
      a4 += hv*g1.x; a5 += hv*g1.y; a6 += hv*g1.z; a7 += hv*g1.w;
    }
  }
  float acc[8] = {a0,a1,a2,a3,a4,a5,a6,a7};
#pragma unroll
  for (int j = 0; j < 8; ++j) {
#pragma unroll
    for (int sh = 32; sh; sh >>= 1) acc[j] += __shfl_xor(acc[j], sh);
  }
  if (lane == 0) {
#pragma unroll
    for (int j = 0; j < 8; ++j) R[(size_t)p * 8 + j] = acc[j];
  }
}

// ---- layer-1 gate from pair logits (top-2 only, no atomics) ----
__global__ __launch_bounds__(256) void gate1_kernel(const float* __restrict__ R,
    const float* __restrict__ b2g, const float* __restrict__ gb,
    int* __restrict__ topk_idx, float* __restrict__ topk_w)
{
  int t = blockIdx.x * 256 + threadIdx.x;
  int v0 = topk_idx[t*2], v1 = topk_idx[t*2+1];
  int e0 = v0 & 7, e1 = v1 & 7;
  int s0 = v0 >> 3, s1 = v1 >> 3;
  double w0 = (double)topk_w[t*2], w1 = (double)topk_w[t*2+1];
  double a[8];
#pragma unroll
  for (int j = 0; j < 8; ++j)
    a[j] = w0 * ((double)R[(size_t)s0*8+j] + (double)b2g[e0*8+j])
         + w1 * ((double)R[(size_t)s1*8+j] + (double)b2g[e1*8+j])
         + (double)gb[j];
  double m = a[0];
  for (int j = 1; j < 8; ++j) m = a[j] > m ? a[j] : m;
  double p[8], sum = 0.0;
  for (int j = 0; j < 8; ++j) { p[j] = exp(a[j] - m); sum += p[j]; }
  for (int j = 0; j < 8; ++j) p[j] /= sum;
  int j0 = 0; double b0 = p[0];
  for (int j = 1; j < 8; ++j) if (p[j] > b0) { b0 = p[j]; j0 = j; }
  int j1 = (j0 == 0) ? 1 : 0; double b1v = p[j1];
  for (int j = 0; j < 8; ++j) if (j != j0 && p[j] > b1v) { b1v = p[j]; j1 = j; }
  topk_idx[t*2]   = j0; topk_idx[t*2+1] = j1;
  topk_w[t*2]     = (float)b0; topk_w[t*2+1] = (float)b1v;
}

// ====== 128x128 grouped GEMM, BK=32, ring-2, 32KB LDS, tile-table grid ======
// A' = [Ah | Al | Ah] (NSEG=3) pairs with B' = [Bh ; Bh ; Bl]  => AhBh + AlBh + AhBl
// MODE 0: outh = bf16(gelu(acc+bias));  MODE 1: split-bf16 out;
// MODE 2: y[slot] = acc+bias (f32 rows, no gelu) — combined later
template<int K0, int NSEG, int NTOT, bool GATHER, int MODE>
__global__ __launch_bounds__(256, 4) void gemm128_kernel(
    const u16* __restrict__ Ah, const u16* __restrict__ Al,
    const u16* __restrict__ Bh, const u16* __restrict__ Bl,
    const float* __restrict__ bias, const int* __restrict__ off,
    const int* __restrict__ tiletab, const int* __restrict__ pair_token,
    u16* __restrict__ outh, u16* __restrict__ outl, float* __restrict__ outy)
{
  constexpr int NT = (K0 * NSEG) / 32;
  const int tt = tiletab[blockIdx.y];
  if (tt < 0) return;
  const int e  = tt >> 16;
  const int mt = tt & 0xffff;
  const int off_e = off[e], off_e1 = off[e + 1];
  const int p0 = off_e + mt * 128;
  const int NX = gridDim.x;
  int bx = blockIdx.x;
  int ntile = ((NX & 7) == 0) ? ((bx & 7) * (NX >> 3) + (bx >> 3)) : bx;
  const int n0 = ntile * 128;

  __shared__ __align__(16) u16 AL[2][4096];
  __shared__ __align__(16) u16 BL[2][4096];

  const int tid  = threadIdx.x;
  const int lane = tid & 63;
  const int wave = tid >> 6;
  const int wm = wave >> 1, wn = wave & 1;
  const int wbase = tid & 192;  // wave*64

  // staging addressing: c = i*256+tid; row r=c>>2; chunk cl=c&3; source pre-swizzled
  size_t aoff[2], boff[2];
#pragma unroll
  for (int i = 0; i < 2; ++i) {
    int c = i * 256 + tid;
    int r = c >> 2;
    int cs = (c & 3) ^ ((r >> 1) & 3);
    int idx = p0 + r;
    if (idx >= off_e1) idx = p0;
    int ar = GATHER ? pair_token[idx] : idx;
    aoff[i] = (size_t)ar * K0 + (size_t)(cs * 8);
    boff[i] = ((size_t)e * NTOT + n0 + r) * K0 + (size_t)(cs * 8);
  }

  auto stage = [&](int b, int t) {
    int kk = t * 32;
    int seg = (NSEG == 3) ? (kk >> 10) : 0;
    int kc  = (NSEG == 3) ? (kk & (K0 - 1)) : kk;
    const u16* abase = ((NSEG == 3 && seg == 1) ? Al : Ah) + kc;
    const u16* bbase = ((NSEG == 3 && seg == 2) ? Bl : Bh) + kc;
#pragma unroll
    for (int i = 0; i < 2; ++i) {
      int cb = i * 256 + wbase;
      gll16(abase + aoff[i], &AL[b][cb * 8]);
      gll16(bbase + boff[i], &BL[b][cb * 8]);
    }
  };

  f32x4 acc[4][4];
  const f32x4 fzero = {0.f, 0.f, 0.f, 0.f};
#pragma unroll
  for (int m = 0; m < 4; ++m)
#pragma unroll
    for (int n = 0; n < 4; ++n) acc[m][n] = fzero;

  stage(0, 0);
  __syncthreads();

  int buf = 0;
  for (int t = 0; t < NT; ++t) {
    if (t + 1 < NT) stage(buf ^ 1, t + 1);
    bf16x8 af[4], bf[4];
#pragma unroll
    for (int m = 0; m < 4; ++m) {
      int row = wm * 64 + m * 16 + (lane & 15);
      af[m] = *(const bf16x8*)&AL[buf][row * 32 + (((lane >> 4) ^ ((row >> 1) & 3)) << 3)];
    }
#pragma unroll
    for (int n = 0; n < 4; ++n) {
      int row = wn * 64 + n * 16 + (lane & 15);
      bf[n] = *(const bf16x8*)&BL[buf][row * 32 + (((lane >> 4) ^ ((row >> 1) & 3)) << 3)];
    }
    __builtin_amdgcn_s_setprio(1);
#pragma unroll
    for (int m = 0; m < 4; ++m)
#pragma unroll
      for (int n = 0; n < 4; ++n)
        acc[m][n] = __builtin_amdgcn_mfma_f32_16x16x32_bf16(af[m], bf[n], acc[m][n], 0, 0, 0);
    __builtin_amdgcn_s_setprio(0);
    __syncthreads();
    buf ^= 1;
  }

  // ---- epilogue ----
  float bv[4];
#pragma unroll
  for (int n = 0; n < 4; ++n)
    bv[n] = bias[(size_t)e * NTOT + n0 + wn * 64 + n * 16 + (lane & 15)];

#pragma unroll
  for (int m = 0; m < 4; ++m) {
    int rbase = p0 + wm * 64 + m * 16 + ((lane >> 4) << 2);
#pragma unroll
    for (int n = 0; n < 4; ++n) {
      int col = n0 + wn * 64 + n * 16 + (lane & 15);
#pragma unroll
      for (int r = 0; r < 4; ++r) {
        int rowp = rbase + r;
        if (rowp < off_e1) {
          float v = acc[m][n][r] + bv[n];
          if constexpr (MODE <= 1) {
            v = 0.5f * v * (1.0f + erff(v * 0.70710678118654752f));
            u16 hb = f2bf(v);
            outh[(size_t)rowp * NTOT + col] = hb;
            if constexpr (MODE == 1)
              outl[(size_t)rowp * NTOT + col] = f2bf(v - bf2f(hb));
          } else {
            outy[(size_t)rowp * NTOT + col] = v;
          }
        }
      }
    }
  }
}

// ---------------- combine (layer 0): xh = bf16(w0*y[s0] + w1*y[s1]) ----------------
__global__ __launch_bounds__(256) void combine0_kernel(const float* __restrict__ y,
    const int* __restrict__ topk_idx, const float* __restrict__ topk_w,
    u16* __restrict__ xh)
{
  int t = blockIdx.x;
  int d = threadIdx.x * 4;
  int s0 = topk_idx[t*2] >> 3, s1 = topk_idx[t*2 + 1] >> 3;
  float w0 = topk_w[t*2], w1 = topk_w[t*2 + 1];
  f32x4 y0 = *(const f32x4*)(y + (size_t)s0 * DM + d);
  f32x4 y1 = *(const f32x4*)(y + (size_t)s1 * DM + d);
  f32x4 v = y0 * w0 + y1 * w1;
  u16x4 hv;
#pragma unroll
  for (int j = 0; j < 4; ++j) hv[j] = f2bf(v[j]);
  *(u16x4*)(xh + (size_t)t * DM + d) = hv;
}

// ---------------- combine (layer 1) + final LayerNorm -> d_out ----------------
__global__ __launch_bounds__(256) void combine1_ln_kernel(const float* __restrict__ y,
    const int* __restrict__ topk_idx, const float* __restrict__ topk_w,
    const float* __restrict__ g, const float* __restrict__ b, float* __restrict__ out)
{
  int t = blockIdx.x;
  int d = threadIdx.x * 4;
  int s0 = topk_idx[t*2] >> 3, s1 = topk_idx[t*2 + 1] >> 3;
  float w0 = topk_w[t*2], w1 = topk_w[t*2 + 1];
  f32x4 y0 = *(const f32x4*)(y + (size_t)s0 * DM + d);
  f32x4 y1 = *(const f32x4*)(y + (size_t)s1 * DM + d);
  f32x4 v = y0 * w0 + y1 * w1;
  float s = v.x + v.y + v.z + v.w;
  float sq = v.x*v.x + v.y*v.y + v.z*v.z + v.w*v.w;
#pragma unroll
  for (int sh = 32; sh; sh >>= 1) { s += __shfl_xor(s, sh); sq += __shfl_xor(sq, sh); }
  __shared__ float red[8];
  int wave = threadIdx.x >> 6, lane = threadIdx.x & 63;
  if (lane == 0) { red[wave] = s; red[4 + wave] = sq; }
  __syncthreads();
  s = red[0] + red[1] + red[2] + red[3];
  sq = red[4] + red[5] + red[6] + red[7];
  float mu = s * (1.0f / DM);
  float var = sq * (1.0f / DM) - mu * mu;
  float inv = rsqrtf(var + LN_EPS);
  f32x4 gv = *(const f32x4*)(g + d);
  f32x4 bv = *(const f32x4*)(b + d);
  f32x4 o;
  o.x = (v.x - mu) * inv * gv.x + bv.x;
  o.y = (v.y - mu) * inv * gv.y + bv.y;
  o.z = (v.z - mu) * inv * gv.z + bv.z;
  o.w = (v.w - mu) * inv * gv.w + bv.w;
  *(f32x4*)(out + (size_t)t * DM + d) = o;
}

extern "C" void kernel_launch(void* const* d_in, const int* in_sizes, int n_in,
                              void* d_out, int out_size, void* d_ws, size_t ws_size,
                              hipStream_t stream)
{
  const int*   tokens = (const int*)d_in[0];
  const float* sym    = (const float*)d_in[1];
  const float* emb    = (const float*)d_in[2];
  const float* gate_w = (const float*)d_in[3];
  const float* gate_b = (const float*)d_in[4];
  const float* w1     = (const float*)d_in[5];
  const float* b1     = (const float*)d_in[6];
  const float* w2     = (const float*)d_in[7];
  const float* b2     = (const float*)d_in[8];
  const float* ln_g   = (const float*)d_in[9];
  const float* ln_b   = (const float*)d_in[10];

  char* ws = (char*)d_ws;
  float* x   = (float*)(ws);                     //  32MB  f32 [8192][1024]
  u16*   xh  = (u16*)  (ws + 33554432);          //  16MB
  u16*   xl  = (u16*)  (ws + 50331648);          //  16MB
  u16*   hh  = (u16*)  (ws + 67108864);          // 128MB  [16384][4096]
  u16*   hl  = (u16*)  (ws + 201326592);         // 128MB (layer-0 GEMM1 only)
  float* y   = (float*)(ws + 201326592);         //  67MB  [16384][1024] (after pairlogit)
  u16*   wTh = (u16*)  (ws + 335544320);         //  64MB
  u16*   wTl = (u16*)  (ws + 402653184);         //  64MB (layer-0 GEMM1 only)
  float* W2G = (float*)(ws + 402653184);         //   1MB  (after GEMM1-L0)
  float* R   = (float*)(ws + 403701760);         // 512KB
  float* B2G = (float*)(ws + 404226048);         //  256B
  int*   pair_token = (int*)  (ws + 469762048);  //  64KB
  int*   topk_idx   = (int*)  (ws + 469893120);  //  64KB (expert | slot<<3)
  float* topk_w     = (float*)(ws + 469958656);  //  64KB
  int*   meta       = (int*)  (ws + 470024192);  //  ~3KB (totals/offsets/tiletab/blockcnt/blockbase)

  embed_kernel<<<T_TOK, 256, 0, stream>>>(tokens, sym, emb, x, xh, xl);

  // ================= layer 0 =================
  gate_kernel<<<T_TOK / 4, 256, 0, stream>>>(x, gate_w, gate_b, topk_idx, topk_w);
  count_kernel<<<T_TOK / 256, 256, 0, stream>>>(topk_idx, meta);
  scan_kernel<<<1, 64, 0, stream>>>(meta);
  scatter_kernel<<<T_TOK / 256, 256, 0, stream>>>(topk_idx, meta, pair_token);

  transpose_kernel<true><<<dim3(DFF / 64, DM / 64, NE), 256, 0, stream>>>(
      w1, wTh, wTl, DM, DFF);
  gemm128_kernel<DM, 3, DFF, true, 1><<<dim3(DFF / 128, MAXTILE), 256, 0, stream>>>(
      xh, xl, wTh, wTl, b1, meta + 8, meta + 32, pair_token, hh, hl, nullptr);

  w2g_kernel<<<NE * DFF / 4, 256, 0, stream>>>(w2, gate_w + (size_t)DM * NE, W2G);
  b2g_kernel<<<16, 256, 0, stream>>>(b2, gate_w + (size_t)DM * NE, B2G);
  pairlogit_kernel<<<NPAIR / 4, 256, 0, stream>>>(hh, hl, meta + 8, W2G, R);

  transpose_kernel<false><<<dim3(DM / 64, DFF / 64, NE), 256, 0, stream>>>(
      w2, wTh, wTl, DFF, DM);
  gemm128_kernel<DFF, 1, DM, false, 2><<<dim3(DM / 128, MAXTILE), 256, 0, stream>>>(
      hh, nullptr, wTh, nullptr, b2, meta + 8, meta + 32, pair_token,
      nullptr, nullptr, y);

  combine0_kernel<<<T_TOK, 256, 0, stream>>>(y, topk_idx, topk_w, xh);

  // ================= layer 1 =================
  gate1_kernel<<<T_TOK / 256, 256, 0, stream>>>(R, B2G, gate_b + NE,
                                                topk_idx, topk_w);
  count_kernel<<<T_TOK / 256, 256, 0, stream>>>(topk_idx, meta);
  scan_kernel<<<1, 64, 0, stream>>>(meta);
  scatter_kernel<<<T_TOK / 256, 256, 0, stream>>>(topk_idx, meta, pair_token);

  transpose_kernel<false><<<dim3(DFF / 64, DM / 64, NE), 256, 0, stream>>>(
      w1 + (size_t)NE * DM * DFF, wTh, wTl, DM, DFF);
  gemm128_kernel<DM, 1, DFF, true, 0><<<dim3(DFF / 128, MAXTILE), 256, 0, stream>>>(
      xh, nullptr, wTh, nullptr, b1 + (size_t)NE * DFF, meta + 8, meta + 32,
      pair_token, hh, nullptr, nullptr);

  transpose_kernel<false><<<dim3(DM / 64, DFF / 64, NE), 256, 0, stream>>>(
      w2 + (size_t)NE * DFF * DM, wTh, wTl, DFF, DM);
  gemm128_kernel<DFF, 1, DM, false, 2><<<dim3(DM / 128, MAXTILE), 256, 0, stream>>>(
      hh, nullptr, wTh, nullptr, b2 + (size_t)NE * DM, meta + 8, meta + 32,
      pair_token, nullptr, nullptr, y);

  combine1_ln_kernel<<<T_TOK, 256, 0, stream>>>(y, topk_idx, topk_w,
                                                ln_g, ln_b, (float*)d_out);
}

// Round 10
// 1872.690 us; speedup vs baseline: 1.0012x; 1.0012x over previous
//
#include <hip/hip_runtime.h>
#include <math.h>

#define T_TOK 8192
#define DM 1024
#define DFF 4096
#define NE 8
#define NPAIR 16384
#define MAXTILE 136
#define LN_EPS 1e-5f

typedef __attribute__((ext_vector_type(8))) short bf16x8;
typedef __attribute__((ext_vector_type(4))) float f32x4;
typedef __attribute__((ext_vector_type(4))) unsigned short u16x4;
typedef __attribute__((ext_vector_type(8))) unsigned short u16x8;
typedef unsigned int u32;
typedef unsigned short u16;

__device__ __forceinline__ u16 f2bf(float f) {
  union { float f; u32 u; } v; v.f = f;
  u32 r = (v.u + 0x7fffu + ((v.u >> 16) & 1u)) >> 16;
  return (u16)r;
}
__device__ __forceinline__ float bf2f(u16 h) {
  union { u32 u; float f; } v; v.u = ((u32)h) << 16; return v.f;
}

__device__ __forceinline__ void gll16(const void* g, void* l) {
  __builtin_amdgcn_global_load_lds(
      (const __attribute__((address_space(1))) u32*)g,
      (__attribute__((address_space(3))) u32*)l, 16, 0, 0);
}

// ---------------- embed: x = emb[tok] + sym[b]; plus split bf16 copies ----------------
__global__ __launch_bounds__(256) void embed_kernel(const int* __restrict__ tok,
    const float* __restrict__ sym, const float* __restrict__ emb,
    float* __restrict__ x, u16* __restrict__ xh, u16* __restrict__ xl)
{
  int t = blockIdx.x;
  int b = t >> 11;
  int tk = tok[t];
  int d = threadIdx.x * 4;
  f32x4 e = *(const f32x4*)(emb + (size_t)tk * DM + d);
  f32x4 s = *(const f32x4*)(sym + (size_t)b * DM + d);
  f32x4 v = e + s;
  *(f32x4*)(x + (size_t)t * DM + d) = v;
  u16x4 hv, lv;
#pragma unroll
  for (int j = 0; j < 4; ++j) {
    u16 hb = f2bf(v[j]);
    hv[j] = hb;
    lv[j] = f2bf(v[j] - bf2f(hb));
  }
  *(u16x4*)(xh + (size_t)t * DM + d) = hv;
  *(u16x4*)(xl + (size_t)t * DM + d) = lv;
}

// ---------------- layer-0 gating: f64 logits, top-2 only (no atomics) ----------------
__global__ __launch_bounds__(256) void gate_kernel(const float* __restrict__ x,
    const float* __restrict__ gw, const float* __restrict__ gb,
    int* __restrict__ topk_idx, float* __restrict__ topk_w)
{
  int lane = threadIdx.x & 63;
  int t = blockIdx.x * 4 + (threadIdx.x >> 6);
  const float* xr = x + (size_t)t * DM;
  double a[8] = {0,0,0,0,0,0,0,0};
  for (int i = 0; i < 16; ++i) {
    int d = i * 64 + lane;
    double xv = (double)xr[d];
    const float* g = gw + (size_t)d * NE;
#pragma unroll
    for (int j = 0; j < 8; ++j) a[j] += xv * (double)g[j];
  }
#pragma unroll
  for (int j = 0; j < 8; ++j) {
#pragma unroll
    for (int sh = 32; sh; sh >>= 1) a[j] += __shfl_xor(a[j], sh);
  }
  if (lane == 0) {
#pragma unroll
    for (int j = 0; j < 8; ++j) a[j] += (double)gb[j];
    double m = a[0];
    for (int j = 1; j < 8; ++j) m = a[j] > m ? a[j] : m;
    double p[8], sum = 0.0;
    for (int j = 0; j < 8; ++j) { p[j] = exp(a[j] - m); sum += p[j]; }
    for (int j = 0; j < 8; ++j) p[j] /= sum;
    int j0 = 0; double b0 = p[0];
    for (int j = 1; j < 8; ++j) if (p[j] > b0) { b0 = p[j]; j0 = j; }
    int j1 = (j0 == 0) ? 1 : 0; double b1v = p[j1];
    for (int j = 0; j < 8; ++j) if (j != j0 && p[j] > b1v) { b1v = p[j]; j1 = j; }
    topk_idx[t*2]   = j0; topk_idx[t*2+1] = j1;
    topk_w[t*2]     = (float)b0; topk_w[t*2+1] = (float)b1v;
  }
}

// meta layout (ints): [0..7]=totals, [8..16]=offsets, [31]=ntiles,
//   [32..167]=tile table ((e<<16)|mt, -1 pad), [168..423]=blockcnt[32][8],
//   [424..679]=blockbase[32][8]
__global__ __launch_bounds__(256) void count_kernel(const int* __restrict__ topk_idx,
    int* __restrict__ meta)
{
  __shared__ int hist[8];
  int tid = threadIdx.x;
  if (tid < 8) hist[tid] = 0;
  __syncthreads();
  int t = blockIdx.x * 256 + tid;
  atomicAdd(&hist[topk_idx[t*2] & 7], 1);
  atomicAdd(&hist[topk_idx[t*2+1] & 7], 1);
  __syncthreads();
  if (tid < 8) meta[168 + blockIdx.x * 8 + tid] = hist[tid];
}

__global__ __launch_bounds__(64) void scan_kernel(int* __restrict__ meta)
{
  __shared__ int tot[8], off[9], tb[8];
  int lane = threadIdx.x;
  if (lane < 8) {
    int s = 0;
    for (int b = 0; b < 32; ++b) s += meta[168 + b * 8 + lane];
    tot[lane] = s;
  }
  __syncthreads();
  if (lane == 0) {
    int s = 0, nt = 0;
    for (int e = 0; e < 8; ++e) {
      off[e] = s; s += tot[e];
      tb[e] = nt; nt += (tot[e] + 127) >> 7;
    }
    off[8] = s;
    meta[31] = nt;
    for (int i = nt; i < MAXTILE; ++i) meta[32 + i] = -1;
  }
  __syncthreads();
  if (lane < 9) meta[8 + lane] = off[lane];
  if (lane < 8) {
    meta[lane] = tot[lane];
    int n = (tot[lane] + 127) >> 7;
    for (int i = 0; i < n; ++i) meta[32 + tb[lane] + i] = (lane << 16) | i;
    int run = off[lane];
    for (int b = 0; b < 32; ++b) {
      meta[424 + b * 8 + lane] = run;
      run += meta[168 + b * 8 + lane];
    }
  }
}

// scatter via block-local LDS ranks; packs slot into topk_idx bits [3..]
__global__ __launch_bounds__(256) void scatter_kernel(int* __restrict__ topk_idx,
    const int* __restrict__ meta, int* __restrict__ pair_token)
{
  __shared__ int hist[8];
  __shared__ int base[8];
  int tid = threadIdx.x;
  if (tid < 8) { hist[tid] = 0; base[tid] = meta[424 + blockIdx.x * 8 + tid]; }
  __syncthreads();
  int t = blockIdx.x * 256 + tid;
#pragma unroll
  for (int k = 0; k < 2; ++k) {
    int e = topk_idx[t*2 + k] & 7;
    int pos = atomicAdd(&hist[e], 1);
    int slot = base[e] + pos;
    pair_token[slot] = t;
    topk_idx[t*2 + k] = e | (slot << 3);
  }
}

// ------------- weight transpose+split: f32 [K][N] -> bf16 hi/lo [N][K] -------------
template<bool LO>
__global__ __launch_bounds__(256) void transpose_kernel(const float* __restrict__ src,
    u16* __restrict__ dsth, u16* __restrict__ dstl, int K, int N)
{
  __shared__ float tile[64][65];
  int e = blockIdx.z;
  const float* s = src + (size_t)e * K * N;
  size_t dbase = (size_t)e * K * N;
  int n0 = blockIdx.x * 64, k0 = blockIdx.y * 64;
  int tid = threadIdx.x;
  int nl = tid & 63;
  int kq = tid >> 6;
#pragma unroll
  for (int j = 0; j < 16; ++j) {
    int kl = j * 4 + kq;
    tile[nl][kl] = s[(size_t)(k0 + kl) * N + n0 + nl];
  }
  __syncthreads();
#pragma unroll
  for (int it = 0; it < 2; ++it) {
    int task = it * 256 + tid;
    int nr = task >> 3;
    int ch = task & 7;
    u16x8 oh, ol;
#pragma unroll
    for (int j = 0; j < 8; ++j) {
      float v = tile[nr][ch*8 + j];
      u16 hb = f2bf(v);
      oh[j] = hb;
      if (LO) ol[j] = f2bf(v - bf2f(hb));
    }
    size_t doff = dbase + (size_t)(n0 + nr) * K + k0 + ch*8;
    *(u16x8*)(dsth + doff) = oh;
    if (LO) *(u16x8*)(dstl + doff) = ol;
  }
}

// ---- W2G[e] = w2[e] @ gw1  ([E][DFF][8], f32) ----
__global__ __launch_bounds__(256) void w2g_kernel(const float* __restrict__ w2,
    const float* __restrict__ gw, float* __restrict__ w2g)
{
  int wid = blockIdx.x * 4 + (threadIdx.x >> 6);
  int lane = threadIdx.x & 63;
  int e = wid >> 12, f = wid & 4095;
  const float* row = w2 + ((size_t)e * DFF + f) * DM;
  float a0=0,a1=0,a2=0,a3=0,a4=0,a5=0,a6=0,a7=0;
  for (int i = 0; i < 4; ++i) {
    int d0 = i * 256 + lane * 4;
    f32x4 xv = *(const f32x4*)(row + d0);
#pragma unroll
    for (int q = 0; q < 4; ++q) {
      const f32x4* gr = (const f32x4*)(gw + (size_t)(d0 + q) * 8);
      f32x4 g0 = gr[0], g1 = gr[1];
      float xq = xv[q];
      a0 += xq*g0.x; a1 += xq*g0.y; a2 += xq*g0.z; a3 += xq*g0.w;
      a4 += xq*g1.x; a5 += xq*g1.y; a6 += xq*g1.z; a7 += xq*g1.w;
    }
  }
  float acc[8] = {a0,a1,a2,a3,a4,a5,a6,a7};
#pragma unroll
  for (int j = 0; j < 8; ++j) {
#pragma unroll
    for (int sh = 32; sh; sh >>= 1) acc[j] += __shfl_xor(acc[j], sh);
  }
  if (lane == 0) {
#pragma unroll
    for (int j = 0; j < 8; ++j) w2g[(size_t)wid * 8 + j] = acc[j];
  }
}

__global__ __launch_bounds__(256) void b2g_kernel(const float* __restrict__ b2,
    const float* __restrict__ gw, float* __restrict__ b2g)
{
  int w = blockIdx.x * 4 + (threadIdx.x >> 6);
  int lane = threadIdx.x & 63;
  int e = w >> 3, j = w & 7;
  float acc = 0.f;
  for (int i = 0; i < 16; ++i) {
    int d = i * 64 + lane;
    acc += b2[(size_t)e * DM + d] * gw[(size_t)d * 8 + j];
  }
#pragma unroll
  for (int sh = 32; sh; sh >>= 1) acc += __shfl_xor(acc, sh);
  if (lane == 0) b2g[w] = acc;
}

// ---- pair logits: R[p] = (hh[p]+hl[p]) @ W2G[e(p)] ----
__global__ __launch_bounds__(256) void pairlogit_kernel(const u16* __restrict__ hh,
    const u16* __restrict__ hl, const int* __restrict__ off,
    const float* __restrict__ w2g, float* __restrict__ R)
{
  int p = blockIdx.x * 4 + (threadIdx.x >> 6);
  int lane = threadIdx.x & 63;
  int e = 0;
#pragma unroll
  for (int j = 1; j < 8; ++j) e += (p >= off[j]) ? 1 : 0;
  const float* wg = w2g + (size_t)e * DFF * 8;
  const u16* ph = hh + (size_t)p * DFF;
  const u16* pl = hl + (size_t)p * DFF;
  float a0=0,a1=0,a2=0,a3=0,a4=0,a5=0,a6=0,a7=0;
  for (int i = 0; i < 8; ++i) {
    int f0 = i * 512 + lane * 8;
    u16x8 vh = *(const u16x8*)(ph + f0);
    u16x8 vl = *(const u16x8*)(pl + f0);
#pragma unroll
    for (int q = 0; q < 8; ++q) {
      float hv = bf2f(vh[q]) + bf2f(vl[q]);
      const f32x4* wr = (const f32x4*)(wg + (size_t)(f0 + q) * 8);
      f32x4 g0 = wr[0], g1 = wr[1];
      a0 += hv*g0.x; a1 += hv*g0.y; a2 += hv*g0.z; a3 += hv*g0.w;
      a4 += hv*g1.x; a5 += hv*g1.y; a6 += hv*g1.z; a7 += hv*g1.w;
    }
  }
  float acc[8] = {a0,a1,a2,a3,a4,a5,a6,a7};
#pragma unroll
  for (int j = 0; j < 8; ++j) {
#pragma unroll
    for (int sh = 32; sh; sh >>= 1) acc[j] += __shfl_xor(acc[j], sh);
  }
  if (lane == 0) {
#pragma unroll
    for (int j = 0; j < 8; ++j) R[(size_t)p * 8 + j] = acc[j];
  }
}

// ---- layer-1 gate from pair logits (top-2 only, no atomics) ----
__global__ __launch_bounds__(256) void gate1_kernel(const float* __restrict__ R,
    const float* __restrict__ b2g, const float* __restrict__ gb,
    int* __restrict__ topk_idx, float* __restrict__ topk_w)
{
  int t = blockIdx.x * 256 + threadIdx.x;
  int v0 = topk_idx[t*2], v1 = topk_idx[t*2+1];
  int e0 = v0 & 7, e1 = v1 & 7;
  int s0 = v0 >> 3, s1 = v1 >> 3;
  double w0 = (double)topk_w[t*2], w1 = (double)topk_w[t*2+1];
  double a[8];
#pragma unroll
  for (int j = 0; j < 8; ++j)
    a[j] = w0 * ((double)R[(size_t)s0*8+j] + (double)b2g[e0*8+j])
         + w1 * ((double)R[(size_t)s1*8+j] + (double)b2g[e1*8+j])
         + (double)gb[j];
  double m = a[0];
  for (int j = 1; j < 8; ++j) m = a[j] > m ? a[j] : m;
  double p[8], sum = 0.0;
  for (int j = 0; j < 8; ++j) { p[j] = exp(a[j] - m); sum += p[j]; }
  for (int j = 0; j < 8; ++j) p[j] /= sum;
  int j0 = 0; double b0 = p[0];
  for (int j = 1; j < 8; ++j) if (p[j] > b0) { b0 = p[j]; j0 = j; }
  int j1 = (j0 == 0) ? 1 : 0; double b1v = p[j1];
  for (int j = 0; j < 8; ++j) if (j != j0 && p[j] > b1v) { b1v = p[j]; j1 = j; }
  topk_idx[t*2]   = j0; topk_idx[t*2+1] = j1;
  topk_w[t*2]     = (float)b0; topk_w[t*2+1] = (float)b1v;
}

// ====== 128x128 grouped GEMM, BK=32, ring-2, 32KB LDS, tile-table grid ======
// A' = [Ah | Al | Ah] (NSEG=3) pairs with B' = [Bh ; Bh ; Bl]  => AhBh + AlBh + AhBl
// MODE 0: outh = bf16(gelu(acc+bias));  MODE 1: split-bf16 out;
// MODE 2: y[slot] = acc+bias (f32 rows, no gelu) — combined later
template<int K0, int NSEG, int NTOT, bool GATHER, int MODE>
__global__ __launch_bounds__(256, 4) void gemm128_kernel(
    const u16* __restrict__ Ah, const u16* __restrict__ Al,
    const u16* __restrict__ Bh, const u16* __restrict__ Bl,
    const float* __restrict__ bias, const int* __restrict__ off,
    const int* __restrict__ tiletab, const int* __restrict__ pair_token,
    u16* __restrict__ outh, u16* __restrict__ outl, float* __restrict__ outy)
{
  constexpr int NT = (K0 * NSEG) / 32;
  const int tt = tiletab[blockIdx.y];
  if (tt < 0) return;
  const int e  = tt >> 16;
  const int mt = tt & 0xffff;
  const int off_e = off[e], off_e1 = off[e + 1];
  const int p0 = off_e + mt * 128;
  const int NX = gridDim.x;
  int bx = blockIdx.x;
  int ntile = ((NX & 7) == 0) ? ((bx & 7) * (NX >> 3) + (bx >> 3)) : bx;
  const int n0 = ntile * 128;

  __shared__ __align__(16) u16 AL[2][4096];
  __shared__ __align__(16) u16 BL[2][4096];

  const int tid  = threadIdx.x;
  const int lane = tid & 63;
  const int wave = tid >> 6;
  const int wm = wave >> 1, wn = wave & 1;
  const int wbase = tid & 192;  // wave*64

  // staging addressing: c = i*256+tid; row r=c>>2; chunk cl=c&3; source pre-swizzled
  size_t aoff[2], boff[2];
#pragma unroll
  for (int i = 0; i < 2; ++i) {
    int c = i * 256 + tid;
    int r = c >> 2;
    int cs = (c & 3) ^ ((r >> 1) & 3);
    int idx = p0 + r;
    if (idx >= off_e1) idx = p0;
    int ar = GATHER ? pair_token[idx] : idx;
    aoff[i] = (size_t)ar * K0 + (size_t)(cs * 8);
    boff[i] = ((size_t)e * NTOT + n0 + r) * K0 + (size_t)(cs * 8);
  }

  auto stage = [&](int b, int t) {
    int kk = t * 32;
    int seg = (NSEG == 3) ? (kk >> 10) : 0;
    int kc  = (NSEG == 3) ? (kk & (K0 - 1)) : kk;
    const u16* abase = ((NSEG == 3 && seg == 1) ? Al : Ah) + kc;
    const u16* bbase = ((NSEG == 3 && seg == 2) ? Bl : Bh) + kc;
#pragma unroll
    for (int i = 0; i < 2; ++i) {
      int cb = i * 256 + wbase;
      gll16(abase + aoff[i], &AL[b][cb * 8]);
      gll16(bbase + boff[i], &BL[b][cb * 8]);
    }
  };

  f32x4 acc[4][4];
  const f32x4 fzero = {0.f, 0.f, 0.f, 0.f};
#pragma unroll
  for (int m = 0; m < 4; ++m)
#pragma unroll
    for (int n = 0; n < 4; ++n) acc[m][n] = fzero;

  stage(0, 0);
  __syncthreads();

  int buf = 0;
  for (int t = 0; t < NT; ++t) {
    if (t + 1 < NT) stage(buf ^ 1, t + 1);
    bf16x8 af[4], bf[4];
#pragma unroll
    for (int m = 0; m < 4; ++m) {
      int row = wm * 64 + m * 16 + (lane & 15);
      af[m] = *(const bf16x8*)&AL[buf][row * 32 + (((lane >> 4) ^ ((row >> 1) & 3)) << 3)];
    }
#pragma unroll
    for (int n = 0; n < 4; ++n) {
      int row = wn * 64 + n * 16 + (lane & 15);
      bf[n] = *(const bf16x8*)&BL[buf][row * 32 + (((lane >> 4) ^ ((row >> 1) & 3)) << 3)];
    }
    __builtin_amdgcn_s_setprio(1);
#pragma unroll
    for (int m = 0; m < 4; ++m)
#pragma unroll
      for (int n = 0; n < 4; ++n)
        acc[m][n] = __builtin_amdgcn_mfma_f32_16x16x32_bf16(af[m], bf[n], acc[m][n], 0, 0, 0);
    __builtin_amdgcn_s_setprio(0);
    __syncthreads();
    buf ^= 1;
  }

  // ---- epilogue ----
  float bv[4];
#pragma unroll
  for (int n = 0; n < 4; ++n)
    bv[n] = bias[(size_t)e * NTOT + n0 + wn * 64 + n * 16 + (lane & 15)];

#pragma unroll
  for (int m = 0; m < 4; ++m) {
    int rbase = p0 + wm * 64 + m * 16 + ((lane >> 4) << 2);
#pragma unroll
    for (int n = 0; n < 4; ++n) {
      int col = n0 + wn * 64 + n * 16 + (lane & 15);
#pragma unroll
      for (int r = 0; r < 4; ++r) {
        int rowp = rbase + r;
        if (rowp < off_e1) {
          float v = acc[m][n][r] + bv[n];
          if constexpr (MODE <= 1) {
            v = 0.5f * v * (1.0f + erff(v * 0.70710678118654752f));
            u16 hb = f2bf(v);
            outh[(size_t)rowp * NTOT + col] = hb;
            if constexpr (MODE == 1)
              outl[(size_t)rowp * NTOT + col] = f2bf(v - bf2f(hb));
          } else {
            outy[(size_t)rowp * NTOT + col] = v;
          }
        }
      }
    }
  }
}

// ---------------- combine (layer 0): xh = bf16(w0*y[s0] + w1*y[s1]) ----------------
__global__ __launch_bounds__(256) void combine0_kernel(const float* __restrict__ y,
    const int* __restrict__ topk_idx, const float* __restrict__ topk_w,
    u16* __restrict__ xh)
{
  int t = blockIdx.x;
  int d = threadIdx.x * 4;
  int s0 = topk_idx[t*2] >> 3, s1 = topk_idx[t*2 + 1] >> 3;
  float w0 = topk_w[t*2], w1 = topk_w[t*2 + 1];
  f32x4 y0 = *(const f32x4*)(y + (size_t)s0 * DM + d);
  f32x4 y1 = *(const f32x4*)(y + (size_t)s1 * DM + d);
  f32x4 v = y0 * w0 + y1 * w1;
  u16x4 hv;
#pragma unroll
  for (int j = 0; j < 4; ++j) hv[j] = f2bf(v[j]);
  *(u16x4*)(xh + (size_t)t * DM + d) = hv;
}

// ---------------- combine (layer 1) + final LayerNorm -> d_out ----------------
__global__ __launch_bounds__(256) void combine1_ln_kernel(const float* __restrict__ y,
    const int* __restrict__ topk_idx, const float* __restrict__ topk_w,
    const float* __restrict__ g, const float* __restrict__ b, float* __restrict__ out)
{
  int t = blockIdx.x;
  int d = threadIdx.x * 4;
  int s0 = topk_idx[t*2] >> 3, s1 = topk_idx[t*2 + 1] >> 3;
  float w0 = topk_w[t*2], w1 = topk_w[t*2 + 1];
  f32x4 y0 = *(const f32x4*)(y + (size_t)s0 * DM + d);
  f32x4 y1 = *(const f32x4*)(y + (size_t)s1 * DM + d);
  f32x4 v = y0 * w0 + y1 * w1;
  float s = v.x + v.y + v.z + v.w;
  float sq = v.x*v.x + v.y*v.y + v.z*v.z + v.w*v.w;
#pragma unroll
  for (int sh = 32; sh; sh >>= 1) { s += __shfl_xor(s, sh); sq += __shfl_xor(sq, sh); }
  __shared__ float red[8];
  int wave = threadIdx.x >> 6, lane = threadIdx.x & 63;
  if (lane == 0) { red[wave] = s; red[4 + wave] = sq; }
  __syncthreads();
  s = red[0] + red[1] + red[2] + red[3];
  sq = red[4] + red[5] + red[6] + red[7];
  float mu = s * (1.0f / DM);
  float var = sq * (1.0f / DM) - mu * mu;
  float inv = rsqrtf(var + LN_EPS);
  f32x4 gv = *(const f32x4*)(g + d);
  f32x4 bv = *(const f32x4*)(b + d);
  f32x4 o;
  o.x = (v.x - mu) * inv * gv.x + bv.x;
  o.y = (v.y - mu) * inv * gv.y + bv.y;
  o.z = (v.z - mu) * inv * gv.z + bv.z;
  o.w = (v.w - mu) * inv * gv.w + bv.w;
  *(f32x4*)(out + (size_t)t * DM + d) = o;
}

extern "C" void kernel_launch(void* const* d_in, const int* in_sizes, int n_in,
                              void* d_out, int out_size, void* d_ws, size_t ws_size,
                              hipStream_t stream)
{
  const int*   tokens = (const int*)d_in[0];
  const float* sym    = (const float*)d_in[1];
  const float* emb    = (const float*)d_in[2];
  const float* gate_w = (const float*)d_in[3];
  const float* gate_b = (const float*)d_in[4];
  const float* w1     = (const float*)d_in[5];
  const float* b1     = (const float*)d_in[6];
  const float* w2     = (const float*)d_in[7];
  const float* b2     = (const float*)d_in[8];
  const float* ln_g   = (const float*)d_in[9];
  const float* ln_b   = (const float*)d_in[10];

  char* ws = (char*)d_ws;
  float* x   = (float*)(ws);                     //  32MB  f32 [8192][1024]
  u16*   xh  = (u16*)  (ws + 33554432);          //  16MB
  u16*   xl  = (u16*)  (ws + 50331648);          //  16MB
  u16*   hh  = (u16*)  (ws + 67108864);          // 128MB  [16384][4096]
  u16*   hl  = (u16*)  (ws + 201326592);         // 128MB (layer-0 GEMM1 only)
  float* y   = (float*)(ws + 201326592);         //  67MB  [16384][1024] (after pairlogit)
  u16*   wTh = (u16*)  (ws + 335544320);         //  64MB
  u16*   wTl = (u16*)  (ws + 402653184);         //  64MB (layer-0 GEMM1 only)
  float* W2G = (float*)(ws + 402653184);         //   1MB  (after GEMM1-L0)
  float* R   = (float*)(ws + 403701760);         // 512KB
  float* B2G = (float*)(ws + 404226048);         //  256B
  int*   pair_token = (int*)  (ws + 469762048);  //  64KB
  int*   topk_idx   = (int*)  (ws + 469893120);  //  64KB (expert | slot<<3)
  float* topk_w     = (float*)(ws + 469958656);  //  64KB
  int*   meta       = (int*)  (ws + 470024192);  //  ~3KB (totals/offsets/tiletab/blockcnt/blockbase)

  embed_kernel<<<T_TOK, 256, 0, stream>>>(tokens, sym, emb, x, xh, xl);

  // ================= layer 0 =================
  gate_kernel<<<T_TOK / 4, 256, 0, stream>>>(x, gate_w, gate_b, topk_idx, topk_w);
  count_kernel<<<T_TOK / 256, 256, 0, stream>>>(topk_idx, meta);
  scan_kernel<<<1, 64, 0, stream>>>(meta);
  scatter_kernel<<<T_TOK / 256, 256, 0, stream>>>(topk_idx, meta, pair_token);

  transpose_kernel<true><<<dim3(DFF / 64, DM / 64, NE), 256, 0, stream>>>(
      w1, wTh, wTl, DM, DFF);
  gemm128_kernel<DM, 3, DFF, true, 1><<<dim3(DFF / 128, MAXTILE), 256, 0, stream>>>(
      xh, xl, wTh, wTl, b1, meta + 8, meta + 32, pair_token, hh, hl, nullptr);

  w2g_kernel<<<NE * DFF / 4, 256, 0, stream>>>(w2, gate_w + (size_t)DM * NE, W2G);
  b2g_kernel<<<16, 256, 0, stream>>>(b2, gate_w + (size_t)DM * NE, B2G);
  pairlogit_kernel<<<NPAIR / 4, 256, 0, stream>>>(hh, hl, meta + 8, W2G, R);

  transpose_kernel<false><<<dim3(DM / 64, DFF / 64, NE), 256, 0, stream>>>(
      w2, wTh, wTl, DFF, DM);
  gemm128_kernel<DFF, 1, DM, false, 2><<<dim3(DM / 128, MAXTILE), 256, 0, stream>>>(
      hh, nullptr, wTh, nullptr, b2, meta + 8, meta + 32, pair_token,
      nullptr, nullptr, y);

  combine0_kernel<<<T_TOK, 256, 0, stream>>>(y, topk_idx, topk_w, xh);

  // ================= layer 1 =================
  gate1_kernel<<<T_TOK / 256, 256, 0, stream>>>(R, B2G, gate_b + NE,
                                                topk_idx, topk_w);
  count_kernel<<<T_TOK / 256, 256, 0, stream>>>(topk_idx, meta);
  scan_kernel<<<1, 64, 0, stream>>>(meta);
  scatter_kernel<<<T_TOK / 256, 256, 0, stream>>>(topk_idx, meta, pair_token);

  transpose_kernel<false><<<dim3(DFF / 64, DM / 64, NE), 256, 0, stream>>>(
      w1 + (size_t)NE * DM * DFF, wTh, wTl, DM, DFF);
  gemm128_kernel<DM, 1, DFF, true, 0><<<dim3(DFF / 128, MAXTILE), 256, 0, stream>>>(
      xh, nullptr, wTh, nullptr, b1 + (size_t)NE * DFF, meta + 8, meta + 32,
      pair_token, hh, nullptr, nullptr);

  transpose_kernel<false><<<dim3(DM / 64, DFF / 64, NE), 256, 0, stream>>>(
      w2 + (size_t)NE * DFF * DM, wTh, wTl, DFF, DM);
  gemm128_kernel<DFF, 1, DM, false, 2><<<dim3(DM / 128, MAXTILE), 256, 0, stream>>>(
      hh, nullptr, wTh, nullptr, b2 + (size_t)NE * DM, meta + 8, meta + 32,
      pair_token, nullptr, nullptr, y);

  combine1_ln_kernel<<<T_TOK, 256, 0, stream>>>(y, topk_idx, topk_w,
                                                ln_g, ln_b, (float*)d_out);
}